// Round 13
// baseline (79.069 us; speedup 1.0000x reference)
//
#include <hip/hip_runtime.h>
#include <hip/hip_bf16.h>
#include <math.h>

#define BB 4
#define CC 64
#define OC 64
#define HH 128
#define WW 128
#define HP 130
#define WP 130
#define KTOT 1152           // 18 slots * 64 ch
#define NKK 36              // main GEMM K-steps (K=32 each)
#define NKC 18              // offset-conv K-steps (K=576)
#define PIXT 16             // pixels per k_main block (round 13: high occupancy)

// ws layout (float units):
//   xp   : [B][HP][WP][C] f32   = 4,326,400 floats
//   wr8  : [36][4][64][8] bf16  = 73,728 ushort (36,864 float slots)
//   wpm8 : [18][64][8]   bf16   =  9,216 ushort ( 4,608 float slots)
#define XP_OFF 0
#define WR8_OFF 4326400
#define WPM8_OFF (4326400 + 36864)

typedef __attribute__((ext_vector_type(8))) short bf16x8;
typedef __attribute__((ext_vector_type(4))) short bf16x4;
typedef __attribute__((ext_vector_type(4))) float f32x4;

__device__ __forceinline__ unsigned short f2bf(float v) {
    union { float f; unsigned int u; } x; x.f = v;
    unsigned int r = x.u + 0x7FFF + ((x.u >> 16) & 1);   // RNE
    return (unsigned short)(r >> 16);
}

// native HW convert (v_cvt_bf16_f32 / pk-fused by compiler; no inline asm — m240)
__device__ __forceinline__ unsigned short f2bfh(float v) {
    __hip_bfloat16 h = __float2bfloat16(v);
    return *reinterpret_cast<unsigned short*>(&h);
}

// fast transcendentals: v_exp/v_sin/v_cos (+fract pre-reduction, cdna4_isa §3)
__device__ __forceinline__ float fexp_(float x) {          // e^x
    return __builtin_amdgcn_exp2f(x * 1.44269504089f);
}
__device__ __forceinline__ float fsig_(float z) {          // sigmoid
    return __builtin_amdgcn_rcpf(1.f + fexp_(-z));
}
__device__ __forceinline__ float fsin_(float x) {          // sin, radians
    float r = x * 0.15915494309f;
    r = __builtin_amdgcn_fractf(r);
    return __builtin_amdgcn_sinf(r);
}
__device__ __forceinline__ float fcos_(float x) {          // cos, radians
    float r = x * 0.15915494309f;
    r = __builtin_amdgcn_fractf(r);
    return __builtin_amdgcn_cosf(r);
}

// ---------------- k_prep: pad-transpose + border zero + weight packs ----------------
#define NB_TR 1024   // 4 b * 128 h * 2 wtiles
#define NB_BZ 516    // 4*516*64/256
#define NB_WR 288    // 73728/256
#define NB_WPM 36    // 9216/256

__global__ __launch_bounds__(256) void k_prep(
    const float* __restrict__ x,
    const float* __restrict__ w_b, const float* __restrict__ w_c,
    const float* __restrict__ w_p, const float* __restrict__ w_m,
    float* __restrict__ xp, unsigned short* __restrict__ wr8,
    unsigned short* __restrict__ wpm8)
{
    int bi = blockIdx.x;
    int tid = threadIdx.x;
    if (bi < NB_TR) {
        // transpose one (b, h, 64-wide w tile): x[b,c,h,w] -> xp[b,h+1,w+1,c]
        __shared__ float t[64][65];
        int b = bi >> 8;
        int h = (bi >> 1) & 127;
        int w0 = (bi & 1) * 64;
        int lane6 = tid & 63;
        for (int cc = tid >> 6; cc < 64; cc += 4)
            t[cc][lane6] = x[((b * 64 + cc) * 128 + h) * 128 + w0 + lane6];
        __syncthreads();
        for (int wsub = tid >> 6; wsub < 64; wsub += 4)
            xp[((size_t)(b * HP + h + 1) * WP + (w0 + wsub + 1)) * 64 + lane6] = t[lane6][wsub];
        return;
    }
    bi -= NB_TR;
    if (bi < NB_BZ) {
        // zero the padded border of xp
        int idx = bi * 256 + tid;            // < 4*516*64
        int c = idx & 63;
        int tt = idx >> 6;                   // 0..2063
        int b = tt / 516;
        int j = tt % 516;
        int hp, wp;
        if (j < 130)      { hp = 0;       wp = j; }
        else if (j < 260) { hp = 129;     wp = j - 130; }
        else if (j < 388) { hp = j - 259; wp = 0; }
        else              { hp = j - 387; wp = 129; }
        xp[((size_t)(b * HP + hp) * WP + wp) * 64 + c] = 0.f;
        return;
    }
    bi -= NB_BZ;
    if (bi < NB_WR) {
        // main-GEMM A pack: wr8[kk][ot][lane][j] = W[o=ot*16+(lane&15)][k=kk*32+(lane>>4)*8+j]
        int idx = bi * 256 + tid;            // < 73728
        int j    = idx & 7;
        int lane = (idx >> 3) & 63;
        int ot   = (idx >> 9) & 3;
        int kk   = idx >> 11;
        int o  = ot * 16 + (lane & 15);
        int k  = kk * 32 + (lane >> 4) * 8 + j;
        int slot = k >> 6;
        int c    = k & 63;
        float v;
        if (slot < 9) v = w_b[((o * CC + c) * 3 + slot / 3) * 3 + slot % 3];
        else { int n = slot - 9; v = w_c[((o * CC + c) * 3 + n / 3) * 3 + n % 3]; }
        wr8[idx] = f2bf(v);
        return;
    }
    bi -= NB_WR;
    {
        // offset/mask-conv A pack: wpm8[kk][lane][j] = Wpm[ch=lane&15][k=kk*32+(lane>>4)*8+j]
        int idx = bi * 256 + tid;            // < 9216
        if (idx >= NKC * 64 * 8) return;
        int j    = idx & 7;
        int lane = (idx >> 3) & 63;
        int kk   = idx >> 9;                 // 0..17
        int ch = lane & 15;
        int k  = kk * 32 + (lane >> 4) * 8 + j;   // 0..575
        int tap = k >> 6;
        int c   = k & 63;
        float v = 0.f;
        if (ch < 3)       v = w_p[((ch * CC + c) * 3 + tap / 3) * 3 + tap % 3];
        else if (ch < 12) v = w_m[(((ch - 3) * CC + c) * 3 + tap / 3) * 3 + tap % 3];
        wpm8[idx] = f2bf(v);
    }
}

// ---------------- k_main: fused offsets + gather + dual GEMM ----------------
// Round 13: PIXT=16, 256 threads = 4 waves, ONE 16-pixel LDS half (~21 KB)
// -> 7 blocks/CU (vs 2 at PIXT=32). Same verified phase bodies as round 8
// (ph==0, ph2==0 everywhere); per-pixel A/B traffic unchanged. The serial
// phase chain now hides across ~7 resident blocks (latency-bound model, r11/r12).
// LDS U: element (k, p16) at 16B-block blk=(k>>3)*16+(p16^((k>>3)&15)), ushort +(k&7).
__global__ __launch_bounds__(256, 8) void k_main(
    const float* __restrict__ xp, const unsigned short* __restrict__ wr8,
    const unsigned short* __restrict__ wpm8,
    const float* __restrict__ w_p,
    const float* __restrict__ b_p, const float* __restrict__ b_m,
    const float* __restrict__ b_b, float* __restrict__ out)
{
    __shared__ unsigned short U8[18432];       // 36,864 B
    __shared__ float wth[16][9][4];            // f32 theta-channel weights: [cq][tap][e]

    int tid = threadIdx.x;
    int lane = tid & 63;
    int g = tid >> 6;                 // wave 0..3
    int p_sub = lane >> 4;            // 0..3
    int cq = lane & 15;
    int c0 = cq * 4;
    int kq = lane >> 4;

    // XCD-aware swizzle (4096 blocks, divisible by 8)
    int bid = blockIdx.x;
    int swz = (bid & 7) * 512 + (bid >> 3);
    int pixBase = swz * PIXT;

    // fill theta-weight table: wth[cq][tap][e] = w_p[ch=2][c=cq*4+e][tap/3][tap%3]
    for (int i = tid; i < 576; i += 256) {
        int cqi = i / 36;
        int rest = i % 36;
        int tap = rest >> 2;
        int e = rest & 3;
        int c = cqi * 4 + e;
        wth[cqi][tap][e] = w_p[((2 * CC + c) * 3 + tap / 3) * 3 + tap % 3];
    }
    __syncthreads();

    int p_local = g * 4 + p_sub;                 // 0..15
    int p16 = p_local;
    int pix = pixBase + p_local;
    int b = pix >> 14;
    int h = (pix >> 7) & 127;
    int w = pix & 127;
    const float* xb = xp + (size_t)b * HP * WP * 64;

    // ---- phase 1a: fixed taps -> U slots 0..8 (bf16) + f32 theta partial
    float th = 0.f;
#pragma unroll
    for (int tap = 0; tap < 9; ++tap) {
        int ti = tap / 3, tj = tap % 3;
        float4 xv = *(const float4*)&xb[((h + ti) * WP + (w + tj)) * 64 + c0];
        float4 wt = *(const float4*)&wth[cq][tap][0];
        th += xv.x * wt.x + xv.y * wt.y + xv.z * wt.z + xv.w * wt.w;
        int k = tap * 64 + c0;
        int kqt = k >> 3;
        int blk = kqt * 16 + (p16 ^ (kqt & 15));
        bf16x4 pk;
        pk[0] = (short)f2bfh(xv.x); pk[1] = (short)f2bfh(xv.y);
        pk[2] = (short)f2bfh(xv.z); pk[3] = (short)f2bfh(xv.w);
        *(bf16x4*)&U8[blk * 8 + (k & 7)] = pk;
    }
    // reduce theta over the 16 lanes (cq) of the pixel-group
    th += __shfl_xor(th, 1);
    th += __shfl_xor(th, 2);
    th += __shfl_xor(th, 4);
    th += __shfl_xor(th, 8);
    // no __syncthreads (round 8): phase 1b only reads this wave's own
    // U-slots 0..8; other waves' concurrent writes are to disjoint addresses.

    // ---- phase 1b: 12-ch offset/mask conv via MFMA on this wave's own 4 pixels.
    f32x4 ca = {0.f, 0.f, 0.f, 0.f}, cb = {0.f, 0.f, 0.f, 0.f};
    {
        int colp = lane & 3;
        int pabs = g * 4 + colp;         // 0..15 == p16 of that pixel
        const bf16x8* av = (const bf16x8*)wpm8;
#pragma unroll
        for (int kk = 0; kk < NKC; ++kk) {
            bf16x8 a = av[kk * 64 + lane];
            int kqt = kk * 4 + kq;
            int blk = kqt * 16 + (pabs ^ (kqt & 15));
            bf16x8 bf = *(const bf16x8*)&U8[blk * 8];
            if (kk & 1) cb = __builtin_amdgcn_mfma_f32_16x16x32_bf16(a, bf, cb, 0, 0, 0);
            else        ca = __builtin_amdgcn_mfma_f32_16x16x32_bf16(a, bf, ca, 0, 0, 0);
        }
        ca[0] += cb[0]; ca[1] += cb[1]; ca[2] += cb[2]; ca[3] += cb[3];
    }

    // ---- deduped record math ----
    // conv D layout (verified r2/r4): conv[ch] of pixel p lives in lane ((ch>>2)<<4)+p, reg ch&3.
    int base16 = p_sub << 4;
    int chc = (cq < 9) ? (3 + cq) : 3;
    int srcL = ((chc >> 2) << 4) + p_sub;
    float m0 = __shfl(ca[0], srcL);
    float m1 = __shfl(ca[1], srcL);
    float m2 = __shfl(ca[2], srcL);
    float m3 = __shfl(ca[3], srcL);
    int jj = chc & 3;
    float cm = (jj == 0) ? m0 : (jj == 1) ? m1 : (jj == 2) ? m2 : m3;
    float c0v = __shfl(ca[0], p_sub);    // conv[0] (l channel)
    float c1v = __shfl(ca[1], p_sub);    // conv[1] (wd channel)

    float bp0 = b_p[0], bp1 = b_p[1], bp2 = b_p[2];
    float hval = 0.f;
    if (cq == 9)       hval = fsig_(fsin_(c0v + bp0)) * 48.5f + 1.5f;
    else if (cq == 10) hval = fsig_(fsin_(c1v + bp1)) * 48.5f + 1.5f;
    else if (cq == 11) hval = fcos_(fsig_(fsin_(th + bp2)) * 3.1415926f);
    else if (cq == 12) hval = fsin_(fsig_(fsin_(th + bp2)) * 3.1415926f);
    float l  = __shfl(hval, base16 + 9);
    float wd = __shfl(hval, base16 + 10);
    float ct = __shfl(hval, base16 + 11);
    float st = __shfl(hval, base16 + 12);

    // one record per lane (sample n = cq; lanes cq>=9 produce unread garbage)
    unsigned int qpack; float glt, grb, glb, grt;
    {
        int n = (cq < 9) ? cq : 8;
        float mm = fsig_(cm + b_m[n]);
        float pnx = (float)(n / 3 - 1);
        float pny = (float)(n % 3 - 1);
        float px = (float)(h + 1) + (l * (1.f / 3.f)) * pnx;
        float py = (float)(w + 1) + (wd * (1.f / 3.f)) * pny;
        float pxx = px * ct - py * st;
        float pyy = px * st + py * ct;
        float fx = floorf(pxx);
        float fy = floorf(pyy);
        int qltx = min(max((int)fx, 0), HP - 1);
        int qlty = min(max((int)fy, 0), WP - 1);
        int qrbx = min(max((int)fx + 1, 0), HP - 1);
        int qrby = min(max((int)fy + 1, 0), WP - 1);
        float pcx = fminf(fmaxf(pxx, 0.f), (float)(HP - 1));
        float pcy = fminf(fmaxf(pyy, 0.f), (float)(WP - 1));
        float dltx = 1.f + ((float)qltx - pcx);
        float drbx = 1.f - ((float)qrbx - pcx);
        float dlty = 1.f + ((float)qlty - pcy);
        float drby = 1.f - ((float)qrby - pcy);
        glt = dltx * dlty * mm;
        grb = drbx * drby * mm;
        glb = dltx * drby * mm;
        grt = drbx * dlty * mm;
        qpack = (unsigned)qltx | ((unsigned)qlty << 8) |
                ((unsigned)qrbx << 16) | ((unsigned)qrby << 24);
    }

    // ---- hoisted record broadcast: all 9 samples' addresses/weights into regs
    unsigned int qn[9];
    float wlt[9], wrb[9], wlb[9], wrt[9];
#pragma unroll
    for (int n = 0; n < 9; ++n) {
        qn[n]  = __shfl(qpack, base16 + n);
        wlt[n] = __shfl(glt, base16 + n);
        wrb[n] = __shfl(grb, base16 + n);
        wlb[n] = __shfl(glb, base16 + n);
        wrt[n] = __shfl(grt, base16 + n);
    }

    // ---- phase 1c: deformable gathers -> U slots 9..17
#pragma unroll
    for (int n = 0; n < 9; ++n) {
        unsigned int q = qn[n];
        int qltx = q & 255, qlty = (q >> 8) & 255;
        int qrbx = (q >> 16) & 255, qrby = (q >> 24) & 255;
        float4 xlt = *(const float4*)&xb[(qltx * WP + qlty) * 64 + c0];
        float4 xrb = *(const float4*)&xb[(qrbx * WP + qrby) * 64 + c0];
        float4 xlb = *(const float4*)&xb[(qltx * WP + qrby) * 64 + c0];
        float4 xrt = *(const float4*)&xb[(qrbx * WP + qlty) * 64 + c0];
        float g_lt = wlt[n], g_rb = wrb[n], g_lb = wlb[n], g_rt = wrt[n];
        float v0 = g_lt * xlt.x + g_rb * xrb.x + g_lb * xlb.x + g_rt * xrt.x;
        float v1 = g_lt * xlt.y + g_rb * xrb.y + g_lb * xlb.y + g_rt * xrt.y;
        float v2 = g_lt * xlt.z + g_rb * xrb.z + g_lb * xlb.z + g_rt * xrt.z;
        float v3 = g_lt * xlt.w + g_rb * xrb.w + g_lb * xlb.w + g_rt * xrt.w;
        int k = (9 + n) * 64 + c0;
        int kqt = k >> 3;
        int blk = kqt * 16 + (p16 ^ (kqt & 15));
        bf16x4 pk;
        pk[0] = (short)f2bfh(v0); pk[1] = (short)f2bfh(v1);
        pk[2] = (short)f2bfh(v2); pk[3] = (short)f2bfh(v3);
        *(bf16x4*)&U8[blk * 8 + (k & 7)] = pk;
    }
    __syncthreads();

    // ---- phase 2: main GEMM, wave g = o-tile g: 16 o x 16 pixels, K=1152
    int ot = g;
    int pn = lane & 15;
    f32x4 a0 = {0.f, 0.f, 0.f, 0.f}, a1 = {0.f, 0.f, 0.f, 0.f};
    const bf16x8* wv = (const bf16x8*)wr8;
#pragma unroll
    for (int kk = 0; kk < NKK; ++kk) {
        bf16x8 a = wv[(kk * 4 + ot) * 64 + lane];
        int kqt = kk * 4 + kq;
        int blk = kqt * 16 + (pn ^ (kqt & 15));
        bf16x8 bf = *(const bf16x8*)&U8[blk * 8];
        if (kk & 1) a1 = __builtin_amdgcn_mfma_f32_16x16x32_bf16(a, bf, a1, 0, 0, 0);
        else        a0 = __builtin_amdgcn_mfma_f32_16x16x32_bf16(a, bf, a0, 0, 0, 0);
    }

    int pix2 = pixBase + pn;
    int bb2 = pix2 >> 14;
    int hw = pix2 & 16383;
#pragma unroll
    for (int r2 = 0; r2 < 4; ++r2) {
        int o = ot * 16 + kq * 4 + r2;
        out[((size_t)(bb2 * 64 + o)) * 16384 + hw] = a0[r2] + a1[r2] + b_b[o];
    }
}

extern "C" void kernel_launch(void* const* d_in, const int* in_sizes, int n_in,
                              void* d_out, int out_size, void* d_ws, size_t ws_size,
                              hipStream_t stream) {
    const float* x   = (const float*)d_in[0];
    const float* w_b = (const float*)d_in[1];
    const float* b_b = (const float*)d_in[2];
    const float* w_p = (const float*)d_in[3];
    const float* b_p = (const float*)d_in[4];
    const float* w_m = (const float*)d_in[5];
    const float* b_m = (const float*)d_in[6];
    const float* w_c = (const float*)d_in[7];
    float* out = (float*)d_out;

    float* ws = (float*)d_ws;
    float* xp = ws + XP_OFF;
    unsigned short* wr8  = (unsigned short*)(ws + WR8_OFF);
    unsigned short* wpm8 = (unsigned short*)(ws + WPM8_OFF);

    k_prep<<<NB_TR + NB_BZ + NB_WR + NB_WPM, 256, 0, stream>>>(
        x, w_b, w_c, w_p, w_m, xp, wr8, wpm8);
    k_main<<<(BB * HH * WW) / PIXT, 256, 0, stream>>>(
        xp, wr8, wpm8, w_p, b_p, b_m, b_b, out);
}

// Round 14
// 77.445 us; speedup vs baseline: 1.0210x; 1.0210x over previous
//
#include <hip/hip_runtime.h>
#include <hip/hip_bf16.h>
#include <math.h>

#define BB 4
#define CC 64
#define OC 64
#define HH 128
#define WW 128
#define HP 130
#define WP 130
#define KTOT 1152           // 18 slots * 64 ch
#define NKK 36              // main GEMM K-steps (K=32 each)
#define NKC 18              // offset-conv K-steps (K=576)
#define PIXT 32             // pixels per k_main block (r13 sweep: 32 optimal)

// ws layout (float units):
//   xp   : [B][HP][WP][C] f32   = 4,326,400 floats
//   wr8  : [36][4][64][8] bf16  = 73,728 ushort (36,864 float slots)
//   wpm8 : [18][64][8]   bf16   =  9,216 ushort ( 4,608 float slots)
#define XP_OFF 0
#define WR8_OFF 4326400
#define WPM8_OFF (4326400 + 36864)

typedef __attribute__((ext_vector_type(8))) short bf16x8;
typedef __attribute__((ext_vector_type(4))) short bf16x4;
typedef __attribute__((ext_vector_type(4))) float f32x4;

__device__ __forceinline__ unsigned short f2bf(float v) {
    union { float f; unsigned int u; } x; x.f = v;
    unsigned int r = x.u + 0x7FFF + ((x.u >> 16) & 1);   // RNE
    return (unsigned short)(r >> 16);
}

// native HW convert (v_cvt_bf16_f32 / pk-fused by compiler; no inline asm — m240)
__device__ __forceinline__ unsigned short f2bfh(float v) {
    __hip_bfloat16 h = __float2bfloat16(v);
    return *reinterpret_cast<unsigned short*>(&h);
}

// fast transcendentals: v_exp/v_sin/v_cos (+fract pre-reduction, cdna4_isa §3)
__device__ __forceinline__ float fexp_(float x) {          // e^x
    return __builtin_amdgcn_exp2f(x * 1.44269504089f);
}
__device__ __forceinline__ float fsig_(float z) {          // sigmoid
    return __builtin_amdgcn_rcpf(1.f + fexp_(-z));
}
__device__ __forceinline__ float fsin_(float x) {          // sin, radians
    float r = x * 0.15915494309f;
    r = __builtin_amdgcn_fractf(r);
    return __builtin_amdgcn_sinf(r);
}
__device__ __forceinline__ float fcos_(float x) {          // cos, radians
    float r = x * 0.15915494309f;
    r = __builtin_amdgcn_fractf(r);
    return __builtin_amdgcn_cosf(r);
}

// ---------------- k_prep: pad-transpose + border zero + weight packs ----------------
#define NB_TR 1024   // 4 b * 128 h * 2 wtiles
#define NB_BZ 516    // 4*516*64/256
#define NB_WR 288    // 73728/256
#define NB_WPM 36    // 9216/256

__global__ __launch_bounds__(256) void k_prep(
    const float* __restrict__ x,
    const float* __restrict__ w_b, const float* __restrict__ w_c,
    const float* __restrict__ w_p, const float* __restrict__ w_m,
    float* __restrict__ xp, unsigned short* __restrict__ wr8,
    unsigned short* __restrict__ wpm8)
{
    int bi = blockIdx.x;
    int tid = threadIdx.x;
    if (bi < NB_TR) {
        // transpose one (b, h, 64-wide w tile): x[b,c,h,w] -> xp[b,h+1,w+1,c]
        __shared__ float t[64][65];
        int b = bi >> 8;
        int h = (bi >> 1) & 127;
        int w0 = (bi & 1) * 64;
        int lane6 = tid & 63;
        for (int cc = tid >> 6; cc < 64; cc += 4)
            t[cc][lane6] = x[((b * 64 + cc) * 128 + h) * 128 + w0 + lane6];
        __syncthreads();
        for (int wsub = tid >> 6; wsub < 64; wsub += 4)
            xp[((size_t)(b * HP + h + 1) * WP + (w0 + wsub + 1)) * 64 + lane6] = t[lane6][wsub];
        return;
    }
    bi -= NB_TR;
    if (bi < NB_BZ) {
        // zero the padded border of xp
        int idx = bi * 256 + tid;            // < 4*516*64
        int c = idx & 63;
        int tt = idx >> 6;                   // 0..2063
        int b = tt / 516;
        int j = tt % 516;
        int hp, wp;
        if (j < 130)      { hp = 0;       wp = j; }
        else if (j < 260) { hp = 129;     wp = j - 130; }
        else if (j < 388) { hp = j - 259; wp = 0; }
        else              { hp = j - 387; wp = 129; }
        xp[((size_t)(b * HP + hp) * WP + wp) * 64 + c] = 0.f;
        return;
    }
    bi -= NB_BZ;
    if (bi < NB_WR) {
        // main-GEMM A pack: wr8[kk][ot][lane][j] = W[o=ot*16+(lane&15)][k=kk*32+(lane>>4)*8+j]
        int idx = bi * 256 + tid;            // < 73728
        int j    = idx & 7;
        int lane = (idx >> 3) & 63;
        int ot   = (idx >> 9) & 3;
        int kk   = idx >> 11;
        int o  = ot * 16 + (lane & 15);
        int k  = kk * 32 + (lane >> 4) * 8 + j;
        int slot = k >> 6;
        int c    = k & 63;
        float v;
        if (slot < 9) v = w_b[((o * CC + c) * 3 + slot / 3) * 3 + slot % 3];
        else { int n = slot - 9; v = w_c[((o * CC + c) * 3 + n / 3) * 3 + n % 3]; }
        wr8[idx] = f2bf(v);
        return;
    }
    bi -= NB_WR;
    {
        // offset/mask-conv A pack: wpm8[kk][lane][j] = Wpm[ch=lane&15][k=kk*32+(lane>>4)*8+j]
        int idx = bi * 256 + tid;            // < 9216
        if (idx >= NKC * 64 * 8) return;
        int j    = idx & 7;
        int lane = (idx >> 3) & 63;
        int kk   = idx >> 9;                 // 0..17
        int ch = lane & 15;
        int k  = kk * 32 + (lane >> 4) * 8 + j;   // 0..575
        int tap = k >> 6;
        int c   = k & 63;
        float v = 0.f;
        if (ch < 3)       v = w_p[((ch * CC + c) * 3 + tap / 3) * 3 + tap % 3];
        else if (ch < 12) v = w_m[(((ch - 3) * CC + c) * 3 + tap / 3) * 3 + tap % 3];
        wpm8[idx] = f2bf(v);
    }
}

// ---------------- k_main: fused offsets + gather + dual GEMM ----------------
// 512 threads = 8 waves, 32 pixels/block — round 8 structure exactly
// (tiling sweep r11/r13 confirmed PIXT=32 optimal; occupancy pinned at
// ~16 waves/CU by LDS/wave). Round 14 single delta: T5 s_setprio(1)/(0)
// around both MFMA clusters — resident blocks sit at diverse phases
// (attn-like m191 case, +4-7%), so MFMA-phase waves get scheduler priority.
// LDS U: two 16-pixel halves; element (k, p16) at 16B-block blk=(k>>3)*16+(p16^((k>>3)&15)).
__global__ __launch_bounds__(512, 4) void k_main(
    const float* __restrict__ xp, const unsigned short* __restrict__ wr8,
    const unsigned short* __restrict__ wpm8,
    const float* __restrict__ w_p,
    const float* __restrict__ b_p, const float* __restrict__ b_m,
    const float* __restrict__ b_b, float* __restrict__ out)
{
    __shared__ unsigned short U8[2 * 18432];   // 73,728 B
    __shared__ float wth[16][9][4];            // f32 theta-channel weights: [cq][tap][e]

    int tid = threadIdx.x;
    int lane = tid & 63;
    int g = tid >> 6;                 // wave 0..7
    int p_sub = lane >> 4;            // 0..3
    int cq = lane & 15;
    int c0 = cq * 4;

    // XCD-aware swizzle (2048 blocks, divisible by 8)
    int bid = blockIdx.x;
    int swz = (bid & 7) * 256 + (bid >> 3);
    int pixBase = swz * PIXT;

    // fill theta-weight table: wth[cq][tap][e] = w_p[ch=2][c=cq*4+e][tap/3][tap%3]
    for (int i = tid; i < 576; i += 512) {
        int cqi = i / 36;
        int rest = i % 36;
        int tap = rest >> 2;
        int e = rest & 3;
        int c = cqi * 4 + e;
        wth[cqi][tap][e] = w_p[((2 * CC + c) * 3 + tap / 3) * 3 + tap % 3];
    }
    __syncthreads();

    int p_local = g * 4 + p_sub;                 // 0..31
    int ph = p_local >> 4;
    int p16 = p_local & 15;
    int pix = pixBase + p_local;
    int b = pix >> 14;
    int h = (pix >> 7) & 127;
    int w = pix & 127;
    const float* xb = xp + (size_t)b * HP * WP * 64;

    // ---- phase 1a: fixed taps -> U slots 0..8 (bf16) + f32 theta partial
    float th = 0.f;
#pragma unroll
    for (int tap = 0; tap < 9; ++tap) {
        int ti = tap / 3, tj = tap % 3;
        float4 xv = *(const float4*)&xb[((h + ti) * WP + (w + tj)) * 64 + c0];
        float4 wt = *(const float4*)&wth[cq][tap][0];
        th += xv.x * wt.x + xv.y * wt.y + xv.z * wt.z + xv.w * wt.w;
        int k = tap * 64 + c0;
        int kqt = k >> 3;
        int blk = kqt * 16 + (p16 ^ (kqt & 15));
        bf16x4 pk;
        pk[0] = (short)f2bfh(xv.x); pk[1] = (short)f2bfh(xv.y);
        pk[2] = (short)f2bfh(xv.z); pk[3] = (short)f2bfh(xv.w);
        *(bf16x4*)&U8[ph * 18432 + blk * 8 + (k & 7)] = pk;
    }
    // reduce theta over the 16 lanes (cq) of the pixel-group
    th += __shfl_xor(th, 1);
    th += __shfl_xor(th, 2);
    th += __shfl_xor(th, 4);
    th += __shfl_xor(th, 8);
    // no __syncthreads here (round 8) — phase 1b only reads this wave's own
    // U-slots 0..8; other waves' concurrent writes are to disjoint addresses.

    // ---- phase 1b: 12-ch offset/mask conv via MFMA on this wave's own 4 pixels.
    int kq = lane >> 4;
    f32x4 ca = {0.f, 0.f, 0.f, 0.f}, cb = {0.f, 0.f, 0.f, 0.f};
    {
        int colp = lane & 3;
        int pabs = g * 4 + colp;
        int phc = g >> 2;
        int p16c = pabs & 15;
        const bf16x8* av = (const bf16x8*)wpm8;
        __builtin_amdgcn_s_setprio(1);
#pragma unroll
        for (int kk = 0; kk < NKC; ++kk) {
            bf16x8 a = av[kk * 64 + lane];
            int kqt = kk * 4 + kq;
            int blk = kqt * 16 + (p16c ^ (kqt & 15));
            bf16x8 bf = *(const bf16x8*)&U8[phc * 18432 + blk * 8];
            if (kk & 1) cb = __builtin_amdgcn_mfma_f32_16x16x32_bf16(a, bf, cb, 0, 0, 0);
            else        ca = __builtin_amdgcn_mfma_f32_16x16x32_bf16(a, bf, ca, 0, 0, 0);
        }
        __builtin_amdgcn_s_setprio(0);
        ca[0] += cb[0]; ca[1] += cb[1]; ca[2] += cb[2]; ca[3] += cb[3];
    }

    // ---- deduped record math ----
    // conv D layout (verified r2/r4): conv[ch] of pixel p lives in lane ((ch>>2)<<4)+p, reg ch&3.
    int base16 = p_sub << 4;
    int chc = (cq < 9) ? (3 + cq) : 3;
    int srcL = ((chc >> 2) << 4) + p_sub;
    float m0 = __shfl(ca[0], srcL);
    float m1 = __shfl(ca[1], srcL);
    float m2 = __shfl(ca[2], srcL);
    float m3 = __shfl(ca[3], srcL);
    int jj = chc & 3;
    float cm = (jj == 0) ? m0 : (jj == 1) ? m1 : (jj == 2) ? m2 : m3;
    float c0v = __shfl(ca[0], p_sub);    // conv[0] (l channel)
    float c1v = __shfl(ca[1], p_sub);    // conv[1] (wd channel)

    float bp0 = b_p[0], bp1 = b_p[1], bp2 = b_p[2];
    float hval = 0.f;
    if (cq == 9)       hval = fsig_(fsin_(c0v + bp0)) * 48.5f + 1.5f;
    else if (cq == 10) hval = fsig_(fsin_(c1v + bp1)) * 48.5f + 1.5f;
    else if (cq == 11) hval = fcos_(fsig_(fsin_(th + bp2)) * 3.1415926f);
    else if (cq == 12) hval = fsin_(fsig_(fsin_(th + bp2)) * 3.1415926f);
    float l  = __shfl(hval, base16 + 9);
    float wd = __shfl(hval, base16 + 10);
    float ct = __shfl(hval, base16 + 11);
    float st = __shfl(hval, base16 + 12);

    // one record per lane (sample n = cq; lanes cq>=9 produce unread garbage)
    unsigned int qpack; float glt, grb, glb, grt;
    {
        int n = (cq < 9) ? cq : 8;
        float mm = fsig_(cm + b_m[n]);
        float pnx = (float)(n / 3 - 1);
        float pny = (float)(n % 3 - 1);
        float px = (float)(h + 1) + (l * (1.f / 3.f)) * pnx;
        float py = (float)(w + 1) + (wd * (1.f / 3.f)) * pny;
        float pxx = px * ct - py * st;
        float pyy = px * st + py * ct;
        float fx = floorf(pxx);
        float fy = floorf(pyy);
        int qltx = min(max((int)fx, 0), HP - 1);
        int qlty = min(max((int)fy, 0), WP - 1);
        int qrbx = min(max((int)fx + 1, 0), HP - 1);
        int qrby = min(max((int)fy + 1, 0), WP - 1);
        float pcx = fminf(fmaxf(pxx, 0.f), (float)(HP - 1));
        float pcy = fminf(fmaxf(pyy, 0.f), (float)(WP - 1));
        float dltx = 1.f + ((float)qltx - pcx);
        float drbx = 1.f - ((float)qrbx - pcx);
        float dlty = 1.f + ((float)qlty - pcy);
        float drby = 1.f - ((float)qrby - pcy);
        glt = dltx * dlty * mm;
        grb = drbx * drby * mm;
        glb = dltx * drby * mm;
        grt = drbx * dlty * mm;
        qpack = (unsigned)qltx | ((unsigned)qlty << 8) |
                ((unsigned)qrbx << 16) | ((unsigned)qrby << 24);
    }

    // ---- hoisted record broadcast: all 9 samples' addresses/weights into regs
    unsigned int qn[9];
    float wlt[9], wrb[9], wlb[9], wrt[9];
#pragma unroll
    for (int n = 0; n < 9; ++n) {
        qn[n]  = __shfl(qpack, base16 + n);
        wlt[n] = __shfl(glt, base16 + n);
        wrb[n] = __shfl(grb, base16 + n);
        wlb[n] = __shfl(glb, base16 + n);
        wrt[n] = __shfl(grt, base16 + n);
    }

    // ---- phase 1c: deformable gathers -> U slots 9..17 (addresses all ready)
#pragma unroll
    for (int n = 0; n < 9; ++n) {
        unsigned int q = qn[n];
        int qltx = q & 255, qlty = (q >> 8) & 255;
        int qrbx = (q >> 16) & 255, qrby = (q >> 24) & 255;
        float4 xlt = *(const float4*)&xb[(qltx * WP + qlty) * 64 + c0];
        float4 xrb = *(const float4*)&xb[(qrbx * WP + qrby) * 64 + c0];
        float4 xlb = *(const float4*)&xb[(qltx * WP + qrby) * 64 + c0];
        float4 xrt = *(const float4*)&xb[(qrbx * WP + qlty) * 64 + c0];
        float g_lt = wlt[n], g_rb = wrb[n], g_lb = wlb[n], g_rt = wrt[n];
        float v0 = g_lt * xlt.x + g_rb * xrb.x + g_lb * xlb.x + g_rt * xrt.x;
        float v1 = g_lt * xlt.y + g_rb * xrb.y + g_lb * xlb.y + g_rt * xrt.y;
        float v2 = g_lt * xlt.z + g_rb * xrb.z + g_lb * xlb.z + g_rt * xrt.z;
        float v3 = g_lt * xlt.w + g_rb * xrb.w + g_lb * xlb.w + g_rt * xrt.w;
        int k = (9 + n) * 64 + c0;
        int kqt = k >> 3;
        int blk = kqt * 16 + (p16 ^ (kqt & 15));
        bf16x4 pk;
        pk[0] = (short)f2bfh(v0); pk[1] = (short)f2bfh(v1);
        pk[2] = (short)f2bfh(v2); pk[3] = (short)f2bfh(v3);
        *(bf16x4*)&U8[ph * 18432 + blk * 8 + (k & 7)] = pk;
    }
    __syncthreads();

    // ---- phase 2: main GEMM, wave (ot=g&3, ph2=g>>2): 16 o x 16 pixels, K=1152
    int ot = g & 3;
    int ph2 = g >> 2;
    int pn = lane & 15;
    f32x4 a0 = {0.f, 0.f, 0.f, 0.f}, a1 = {0.f, 0.f, 0.f, 0.f};
    const bf16x8* wv = (const bf16x8*)wr8;
    __builtin_amdgcn_s_setprio(1);
#pragma unroll
    for (int kk = 0; kk < NKK; ++kk) {
        bf16x8 a = wv[(kk * 4 + ot) * 64 + lane];
        int kqt = kk * 4 + kq;
        int blk = kqt * 16 + (pn ^ (kqt & 15));
        bf16x8 bf = *(const bf16x8*)&U8[ph2 * 18432 + blk * 8];
        if (kk & 1) a1 = __builtin_amdgcn_mfma_f32_16x16x32_bf16(a, bf, a1, 0, 0, 0);
        else        a0 = __builtin_amdgcn_mfma_f32_16x16x32_bf16(a, bf, a0, 0, 0, 0);
    }
    __builtin_amdgcn_s_setprio(0);

    int pix2 = pixBase + ph2 * 16 + pn;
    int bb2 = pix2 >> 14;
    int hw = pix2 & 16383;
#pragma unroll
    for (int r2 = 0; r2 < 4; ++r2) {
        int o = ot * 16 + kq * 4 + r2;
        out[((size_t)(bb2 * 64 + o)) * 16384 + hw] = a0[r2] + a1[r2] + b_b[o];
    }
}

extern "C" void kernel_launch(void* const* d_in, const int* in_sizes, int n_in,
                              void* d_out, int out_size, void* d_ws, size_t ws_size,
                              hipStream_t stream) {
    const float* x   = (const float*)d_in[0];
    const float* w_b = (const float*)d_in[1];
    const float* b_b = (const float*)d_in[2];
    const float* w_p = (const float*)d_in[3];
    const float* b_p = (const float*)d_in[4];
    const float* w_m = (const float*)d_in[5];
    const float* b_m = (const float*)d_in[6];
    const float* w_c = (const float*)d_in[7];
    float* out = (float*)d_out;

    float* ws = (float*)d_ws;
    float* xp = ws + XP_OFF;
    unsigned short* wr8  = (unsigned short*)(ws + WR8_OFF);
    unsigned short* wpm8 = (unsigned short*)(ws + WPM8_OFF);

    k_prep<<<NB_TR + NB_BZ + NB_WR + NB_WPM, 256, 0, stream>>>(
        x, w_b, w_c, w_p, w_m, xp, wr8, wpm8);
    k_main<<<(BB * HH * WW) / PIXT, 512, 0, stream>>>(
        xp, wr8, wpm8, w_p, b_p, b_m, b_b, out);
}

// Round 15
// 74.817 us; speedup vs baseline: 1.0568x; 1.0351x over previous
//
#include <hip/hip_runtime.h>
#include <hip/hip_bf16.h>
#include <math.h>

#define BB 4
#define CC 64
#define OC 64
#define HH 128
#define WW 128
#define HP 130
#define WP 130
#define KTOT 1152           // 18 slots * 64 ch
#define NKK 36              // main GEMM K-steps (K=32 each)
#define NKC 18              // offset-conv K-steps (K=576)
#define PIXT 32             // pixels per k_main block (r13 sweep: 32 optimal)

// ws layout (float units):
//   xp   : [B][HP][WP][C] f32   = 4,326,400 floats
//   wr8  : [36][4][64][8] bf16  = 73,728 ushort (36,864 float slots)
//   wpm8 : [18][64][8]   bf16   =  9,216 ushort ( 4,608 float slots)
#define XP_OFF 0
#define WR8_OFF 4326400
#define WPM8_OFF (4326400 + 36864)

typedef __attribute__((ext_vector_type(8))) short bf16x8;
typedef __attribute__((ext_vector_type(4))) short bf16x4;
typedef __attribute__((ext_vector_type(4))) float f32x4;

__device__ __forceinline__ unsigned short f2bf(float v) {
    union { float f; unsigned int u; } x; x.f = v;
    unsigned int r = x.u + 0x7FFF + ((x.u >> 16) & 1);   // RNE
    return (unsigned short)(r >> 16);
}

// native HW convert (v_cvt_bf16_f32 / pk-fused by compiler; no inline asm — m240)
__device__ __forceinline__ unsigned short f2bfh(float v) {
    __hip_bfloat16 h = __float2bfloat16(v);
    return *reinterpret_cast<unsigned short*>(&h);
}

// fast transcendentals: v_exp/v_sin/v_cos (+fract pre-reduction, cdna4_isa §3)
__device__ __forceinline__ float fexp_(float x) {          // e^x
    return __builtin_amdgcn_exp2f(x * 1.44269504089f);
}
__device__ __forceinline__ float fsig_(float z) {          // sigmoid
    return __builtin_amdgcn_rcpf(1.f + fexp_(-z));
}
__device__ __forceinline__ float fsin_(float x) {          // sin, radians
    float r = x * 0.15915494309f;
    r = __builtin_amdgcn_fractf(r);
    return __builtin_amdgcn_sinf(r);
}
__device__ __forceinline__ float fcos_(float x) {          // cos, radians
    float r = x * 0.15915494309f;
    r = __builtin_amdgcn_fractf(r);
    return __builtin_amdgcn_cosf(r);
}

// ---------------- k_prep: pad-transpose + border zero + weight packs ----------------
#define NB_TR 1024   // 4 b * 128 h * 2 wtiles
#define NB_BZ 516    // 4*516*64/256
#define NB_WR 288    // 73728/256
#define NB_WPM 36    // 9216/256

__global__ __launch_bounds__(256) void k_prep(
    const float* __restrict__ x,
    const float* __restrict__ w_b, const float* __restrict__ w_c,
    const float* __restrict__ w_p, const float* __restrict__ w_m,
    float* __restrict__ xp, unsigned short* __restrict__ wr8,
    unsigned short* __restrict__ wpm8)
{
    int bi = blockIdx.x;
    int tid = threadIdx.x;
    if (bi < NB_TR) {
        // transpose one (b, h, 64-wide w tile): x[b,c,h,w] -> xp[b,h+1,w+1,c]
        __shared__ float t[64][65];
        int b = bi >> 8;
        int h = (bi >> 1) & 127;
        int w0 = (bi & 1) * 64;
        int lane6 = tid & 63;
        for (int cc = tid >> 6; cc < 64; cc += 4)
            t[cc][lane6] = x[((b * 64 + cc) * 128 + h) * 128 + w0 + lane6];
        __syncthreads();
        for (int wsub = tid >> 6; wsub < 64; wsub += 4)
            xp[((size_t)(b * HP + h + 1) * WP + (w0 + wsub + 1)) * 64 + lane6] = t[lane6][wsub];
        return;
    }
    bi -= NB_TR;
    if (bi < NB_BZ) {
        // zero the padded border of xp
        int idx = bi * 256 + tid;            // < 4*516*64
        int c = idx & 63;
        int tt = idx >> 6;                   // 0..2063
        int b = tt / 516;
        int j = tt % 516;
        int hp, wp;
        if (j < 130)      { hp = 0;       wp = j; }
        else if (j < 260) { hp = 129;     wp = j - 130; }
        else if (j < 388) { hp = j - 259; wp = 0; }
        else              { hp = j - 387; wp = 129; }
        xp[((size_t)(b * HP + hp) * WP + wp) * 64 + c] = 0.f;
        return;
    }
    bi -= NB_BZ;
    if (bi < NB_WR) {
        // main-GEMM A pack: wr8[kk][ot][lane][j] = W[o=ot*16+(lane&15)][k=kk*32+(lane>>4)*8+j]
        int idx = bi * 256 + tid;            // < 73728
        int j    = idx & 7;
        int lane = (idx >> 3) & 63;
        int ot   = (idx >> 9) & 3;
        int kk   = idx >> 11;
        int o  = ot * 16 + (lane & 15);
        int k  = kk * 32 + (lane >> 4) * 8 + j;
        int slot = k >> 6;
        int c    = k & 63;
        float v;
        if (slot < 9) v = w_b[((o * CC + c) * 3 + slot / 3) * 3 + slot % 3];
        else { int n = slot - 9; v = w_c[((o * CC + c) * 3 + n / 3) * 3 + n % 3]; }
        wr8[idx] = f2bf(v);
        return;
    }
    bi -= NB_WR;
    {
        // offset/mask-conv A pack: wpm8[kk][lane][j] = Wpm[ch=lane&15][k=kk*32+(lane>>4)*8+j]
        int idx = bi * 256 + tid;            // < 9216
        if (idx >= NKC * 64 * 8) return;
        int j    = idx & 7;
        int lane = (idx >> 3) & 63;
        int kk   = idx >> 9;                 // 0..17
        int ch = lane & 15;
        int k  = kk * 32 + (lane >> 4) * 8 + j;   // 0..575
        int tap = k >> 6;
        int c   = k & 63;
        float v = 0.f;
        if (ch < 3)       v = w_p[((ch * CC + c) * 3 + tap / 3) * 3 + tap % 3];
        else if (ch < 12) v = w_m[(((ch - 3) * CC + c) * 3 + tap / 3) * 3 + tap % 3];
        wpm8[idx] = f2bf(v);
    }
}

// ---------------- k_main: fused offsets + gather + 2-pass GEMM ----------------
// Round 15: time-multiplexed U buffer. 9-slot LDS U (36.9KB) reused:
//   1a: fixed taps -> slots 0..8          | barrier
//   2a: GEMM kk 0..17 (K 0..575) -> acc   | barrier
//   1c: gathers OVERWRITE slots 0..8      | barrier
//   2b: GEMM kk 18..35 -> same acc        | epilogue
// No cross-wave partials (each wave accumulates full K — r9/r10 failure mode
// structurally absent; arithmetic order identical to round 8).
// Records live in a 5.8KB LDS table instead of 45 VGPRs -> launch_bounds(512,6)
// pins 3 blocks/CU (24 waves vs 16): the occupancy lever r13 showed is the wall.
// LDS U: element (k<576, p16) of half ph at ushort U8[ph*9216 + blk*8 + (k&7)],
// blk = (k>>3)*16 + (p16 ^ ((k>>3)&15)).
__global__ __launch_bounds__(512, 6) void k_main(
    const float* __restrict__ xp, const unsigned short* __restrict__ wr8,
    const unsigned short* __restrict__ wpm8,
    const float* __restrict__ w_p,
    const float* __restrict__ b_p, const float* __restrict__ b_m,
    const float* __restrict__ b_b, float* __restrict__ out)
{
    __shared__ unsigned short U8[2 * 9216];    // 36,864 B (9 slots x 2 halves)
    __shared__ unsigned int rec[32][9][5];     // 5,760 B  sampling records
    __shared__ float wth[16][9][4];            // 2,304 B  theta weights [cq][tap][e]

    int tid = threadIdx.x;
    int lane = tid & 63;
    int g = tid >> 6;                 // wave 0..7
    int p_sub = lane >> 4;            // 0..3
    int cq = lane & 15;
    int c0 = cq * 4;
    int kq = lane >> 4;

    // XCD-aware swizzle (2048 blocks, divisible by 8)
    int bid = blockIdx.x;
    int swz = (bid & 7) * 256 + (bid >> 3);
    int pixBase = swz * PIXT;

    // fill theta-weight table: wth[cq][tap][e] = w_p[ch=2][c=cq*4+e][tap/3][tap%3]
    for (int i = tid; i < 576; i += 512) {
        int cqi = i / 36;
        int rest = i % 36;
        int tap = rest >> 2;
        int e = rest & 3;
        int c = cqi * 4 + e;
        wth[cqi][tap][e] = w_p[((2 * CC + c) * 3 + tap / 3) * 3 + tap % 3];
    }
    __syncthreads();

    int p_local = g * 4 + p_sub;                 // 0..31
    int ph = p_local >> 4;
    int p16 = p_local & 15;
    int pix = pixBase + p_local;
    int b = pix >> 14;
    int h = (pix >> 7) & 127;
    int w = pix & 127;
    const float* xb = xp + (size_t)b * HP * WP * 64;

    // ---- phase 1a: fixed taps -> U slots 0..8 (bf16) + f32 theta partial
    float th = 0.f;
#pragma unroll
    for (int tap = 0; tap < 9; ++tap) {
        int ti = tap / 3, tj = tap % 3;
        float4 xv = *(const float4*)&xb[((h + ti) * WP + (w + tj)) * 64 + c0];
        float4 wt = *(const float4*)&wth[cq][tap][0];
        th += xv.x * wt.x + xv.y * wt.y + xv.z * wt.z + xv.w * wt.w;
        int k = tap * 64 + c0;
        int kqt = k >> 3;
        int blk = kqt * 16 + (p16 ^ (kqt & 15));
        bf16x4 pk;
        pk[0] = (short)f2bfh(xv.x); pk[1] = (short)f2bfh(xv.y);
        pk[2] = (short)f2bfh(xv.z); pk[3] = (short)f2bfh(xv.w);
        *(bf16x4*)&U8[ph * 9216 + blk * 8 + (k & 7)] = pk;
    }
    // reduce theta over the 16 lanes (cq) of the pixel-group
    th += __shfl_xor(th, 1);
    th += __shfl_xor(th, 2);
    th += __shfl_xor(th, 4);
    th += __shfl_xor(th, 8);
    // no barrier: phase 1b reads only this wave's own pixels' slots (written
    // by itself); other waves' concurrent writes hit disjoint addresses.

    // ---- phase 1b: 12-ch offset/mask conv via MFMA on this wave's own 4 pixels.
    f32x4 ca = {0.f, 0.f, 0.f, 0.f}, cb = {0.f, 0.f, 0.f, 0.f};
    {
        int colp = lane & 3;
        int pabs = g * 4 + colp;
        int phc = g >> 2;
        int p16c = pabs & 15;
        const bf16x8* av = (const bf16x8*)wpm8;
#pragma unroll
        for (int kk = 0; kk < NKC; ++kk) {
            bf16x8 a = av[kk * 64 + lane];
            int kqt = kk * 4 + kq;
            int blk = kqt * 16 + (p16c ^ (kqt & 15));
            bf16x8 bf = *(const bf16x8*)&U8[phc * 9216 + blk * 8];
            if (kk & 1) cb = __builtin_amdgcn_mfma_f32_16x16x32_bf16(a, bf, cb, 0, 0, 0);
            else        ca = __builtin_amdgcn_mfma_f32_16x16x32_bf16(a, bf, ca, 0, 0, 0);
        }
        ca[0] += cb[0]; ca[1] += cb[1]; ca[2] += cb[2]; ca[3] += cb[3];
    }

    // ---- deduped record math ----
    // conv D layout (verified r2/r4): conv[ch] of pixel p lives in lane ((ch>>2)<<4)+p, reg ch&3.
    int base16 = p_sub << 4;
    int chc = (cq < 9) ? (3 + cq) : 3;
    int srcL = ((chc >> 2) << 4) + p_sub;
    float m0 = __shfl(ca[0], srcL);
    float m1 = __shfl(ca[1], srcL);
    float m2 = __shfl(ca[2], srcL);
    float m3 = __shfl(ca[3], srcL);
    int jj = chc & 3;
    float cm = (jj == 0) ? m0 : (jj == 1) ? m1 : (jj == 2) ? m2 : m3;
    float c0v = __shfl(ca[0], p_sub);    // conv[0] (l channel)
    float c1v = __shfl(ca[1], p_sub);    // conv[1] (wd channel)

    float bp0 = b_p[0], bp1 = b_p[1], bp2 = b_p[2];
    float hval = 0.f;
    if (cq == 9)       hval = fsig_(fsin_(c0v + bp0)) * 48.5f + 1.5f;
    else if (cq == 10) hval = fsig_(fsin_(c1v + bp1)) * 48.5f + 1.5f;
    else if (cq == 11) hval = fcos_(fsig_(fsin_(th + bp2)) * 3.1415926f);
    else if (cq == 12) hval = fsin_(fsig_(fsin_(th + bp2)) * 3.1415926f);
    float l  = __shfl(hval, base16 + 9);
    float wd = __shfl(hval, base16 + 10);
    float ct = __shfl(hval, base16 + 11);
    float st = __shfl(hval, base16 + 12);

    // one record per lane (sample n = cq); lanes cq<9 store to the LDS table
    {
        int n = (cq < 9) ? cq : 8;
        float mm = fsig_(cm + b_m[n]);
        float pnx = (float)(n / 3 - 1);
        float pny = (float)(n % 3 - 1);
        float px = (float)(h + 1) + (l * (1.f / 3.f)) * pnx;
        float py = (float)(w + 1) + (wd * (1.f / 3.f)) * pny;
        float pxx = px * ct - py * st;
        float pyy = px * st + py * ct;
        float fx = floorf(pxx);
        float fy = floorf(pyy);
        int qltx = min(max((int)fx, 0), HP - 1);
        int qlty = min(max((int)fy, 0), WP - 1);
        int qrbx = min(max((int)fx + 1, 0), HP - 1);
        int qrby = min(max((int)fy + 1, 0), WP - 1);
        float pcx = fminf(fmaxf(pxx, 0.f), (float)(HP - 1));
        float pcy = fminf(fmaxf(pyy, 0.f), (float)(WP - 1));
        float dltx = 1.f + ((float)qltx - pcx);
        float drbx = 1.f - ((float)qrbx - pcx);
        float dlty = 1.f + ((float)qlty - pcy);
        float drby = 1.f - ((float)qrby - pcy);
        float glt = dltx * dlty * mm;
        float grb = drbx * drby * mm;
        float glb = dltx * drby * mm;
        float grt = drbx * dlty * mm;
        unsigned int qpack = (unsigned)qltx | ((unsigned)qlty << 8) |
                             ((unsigned)qrbx << 16) | ((unsigned)qrby << 24);
        if (cq < 9) {
            unsigned int* r = &rec[p_local][cq][0];
            r[0] = qpack;
            r[1] = __float_as_uint(glt);
            r[2] = __float_as_uint(grb);
            r[3] = __float_as_uint(glb);
            r[4] = __float_as_uint(grt);
        }
    }
    __syncthreads();   // barrier 1: all tap-slots + records visible

    // ---- phase 2a: GEMM pass A, kk 0..17 (fixed-tap K range)
    int ot = g & 3;
    int ph2 = g >> 2;
    int pn = lane & 15;
    f32x4 a0 = {0.f, 0.f, 0.f, 0.f}, a1 = {0.f, 0.f, 0.f, 0.f};
    const bf16x8* wv = (const bf16x8*)wr8;
#pragma unroll
    for (int kk = 0; kk < 18; ++kk) {
        bf16x8 a = wv[(kk * 4 + ot) * 64 + lane];
        int kqt = kk * 4 + kq;
        int blk = kqt * 16 + (pn ^ (kqt & 15));
        bf16x8 bf = *(const bf16x8*)&U8[ph2 * 9216 + blk * 8];
        if (kk & 1) a1 = __builtin_amdgcn_mfma_f32_16x16x32_bf16(a, bf, a1, 0, 0, 0);
        else        a0 = __builtin_amdgcn_mfma_f32_16x16x32_bf16(a, bf, a0, 0, 0, 0);
    }
    __syncthreads();   // barrier 2: pass-A reads complete before overwrite

    // ---- phase 1c: deformable gathers OVERWRITE slots 0..8 (records from LDS)
#pragma unroll
    for (int n = 0; n < 9; ++n) {
        const unsigned int* r = &rec[p_local][n][0];
        unsigned int q = r[0];
        float g_lt = __uint_as_float(r[1]);
        float g_rb = __uint_as_float(r[2]);
        float g_lb = __uint_as_float(r[3]);
        float g_rt = __uint_as_float(r[4]);
        int qltx = q & 255, qlty = (q >> 8) & 255;
        int qrbx = (q >> 16) & 255, qrby = (q >> 24) & 255;
        float4 xlt = *(const float4*)&xb[(qltx * WP + qlty) * 64 + c0];
        float4 xrb = *(const float4*)&xb[(qrbx * WP + qrby) * 64 + c0];
        float4 xlb = *(const float4*)&xb[(qltx * WP + qrby) * 64 + c0];
        float4 xrt = *(const float4*)&xb[(qrbx * WP + qlty) * 64 + c0];
        float v0 = g_lt * xlt.x + g_rb * xrb.x + g_lb * xlb.x + g_rt * xrt.x;
        float v1 = g_lt * xlt.y + g_rb * xrb.y + g_lb * xlb.y + g_rt * xrt.y;
        float v2 = g_lt * xlt.z + g_rb * xrb.z + g_lb * xlb.z + g_rt * xrt.z;
        float v3 = g_lt * xlt.w + g_rb * xrb.w + g_lb * xlb.w + g_rt * xrt.w;
        int k = n * 64 + c0;
        int kqt = k >> 3;
        int blk = kqt * 16 + (p16 ^ (kqt & 15));
        bf16x4 pk;
        pk[0] = (short)f2bfh(v0); pk[1] = (short)f2bfh(v1);
        pk[2] = (short)f2bfh(v2); pk[3] = (short)f2bfh(v3);
        *(bf16x4*)&U8[ph * 9216 + blk * 8 + (k & 7)] = pk;
    }
    __syncthreads();   // barrier 3: gather slots visible

    // ---- phase 2b: GEMM pass B, kk 18..35 (gather K range), same accumulators
#pragma unroll
    for (int kk = 18; kk < 36; ++kk) {
        bf16x8 a = wv[(kk * 4 + ot) * 64 + lane];
        int kl = kk - 18;
        int kqt = kl * 4 + kq;
        int blk = kqt * 16 + (pn ^ (kqt & 15));
        bf16x8 bf = *(const bf16x8*)&U8[ph2 * 9216 + blk * 8];
        if (kk & 1) a1 = __builtin_amdgcn_mfma_f32_16x16x32_bf16(a, bf, a1, 0, 0, 0);
        else        a0 = __builtin_amdgcn_mfma_f32_16x16x32_bf16(a, bf, a0, 0, 0, 0);
    }

    int pix2 = pixBase + ph2 * 16 + pn;
    int bb2 = pix2 >> 14;
    int hw = pix2 & 16383;
#pragma unroll
    for (int r2 = 0; r2 < 4; ++r2) {
        int o = ot * 16 + kq * 4 + r2;
        out[((size_t)(bb2 * 64 + o)) * 16384 + hw] = a0[r2] + a1[r2] + b_b[o];
    }
}

extern "C" void kernel_launch(void* const* d_in, const int* in_sizes, int n_in,
                              void* d_out, int out_size, void* d_ws, size_t ws_size,
                              hipStream_t stream) {
    const float* x   = (const float*)d_in[0];
    const float* w_b = (const float*)d_in[1];
    const float* b_b = (const float*)d_in[2];
    const float* w_p = (const float*)d_in[3];
    const float* b_p = (const float*)d_in[4];
    const float* w_m = (const float*)d_in[5];
    const float* b_m = (const float*)d_in[6];
    const float* w_c = (const float*)d_in[7];
    float* out = (float*)d_out;

    float* ws = (float*)d_ws;
    float* xp = ws + XP_OFF;
    unsigned short* wr8  = (unsigned short*)(ws + WR8_OFF);
    unsigned short* wpm8 = (unsigned short*)(ws + WPM8_OFF);

    k_prep<<<NB_TR + NB_BZ + NB_WR + NB_WPM, 256, 0, stream>>>(
        x, w_b, w_c, w_p, w_m, xp, wr8, wpm8);
    k_main<<<(BB * HH * WW) / PIXT, 512, 0, stream>>>(
        xp, wr8, wpm8, w_p, b_p, b_m, b_b, out);
}

// Round 16
// 70.069 us; speedup vs baseline: 1.1284x; 1.0678x over previous
//
#include <hip/hip_runtime.h>
#include <hip/hip_bf16.h>
#include <math.h>

#define BB 4
#define CC 64
#define OC 64
#define HH 128
#define WW 128
#define HP 130
#define WP 130
#define KTOT 1152           // 18 slots * 64 ch
#define NKK 36              // main GEMM K-steps (K=32 each)
#define NKC 18              // offset-conv K-steps (K=576)
#define PIXT 32             // pixels per k_main block (r11/r13 sweep: 32 optimal)

// ws layout (float units):
//   xp   : [B][HP][WP][C] f32   = 4,326,400 floats
//   wr8  : [36][4][64][8] bf16  = 73,728 ushort (36,864 float slots)
//   wpm8 : [18][64][8]   bf16   =  9,216 ushort ( 4,608 float slots)
#define XP_OFF 0
#define WR8_OFF 4326400
#define WPM8_OFF (4326400 + 36864)

typedef __attribute__((ext_vector_type(8))) short bf16x8;
typedef __attribute__((ext_vector_type(4))) short bf16x4;
typedef __attribute__((ext_vector_type(4))) float f32x4;

__device__ __forceinline__ unsigned short f2bf(float v) {
    union { float f; unsigned int u; } x; x.f = v;
    unsigned int r = x.u + 0x7FFF + ((x.u >> 16) & 1);   // RNE
    return (unsigned short)(r >> 16);
}

// native HW convert (v_cvt_bf16_f32 / pk-fused by compiler; no inline asm — m240)
__device__ __forceinline__ unsigned short f2bfh(float v) {
    __hip_bfloat16 h = __float2bfloat16(v);
    return *reinterpret_cast<unsigned short*>(&h);
}

// fast transcendentals: v_exp/v_sin/v_cos (+fract pre-reduction, cdna4_isa §3)
__device__ __forceinline__ float fexp_(float x) {          // e^x
    return __builtin_amdgcn_exp2f(x * 1.44269504089f);
}
__device__ __forceinline__ float fsig_(float z) {          // sigmoid
    return __builtin_amdgcn_rcpf(1.f + fexp_(-z));
}
__device__ __forceinline__ float fsin_(float x) {          // sin, radians
    float r = x * 0.15915494309f;
    r = __builtin_amdgcn_fractf(r);
    return __builtin_amdgcn_sinf(r);
}
__device__ __forceinline__ float fcos_(float x) {          // cos, radians
    float r = x * 0.15915494309f;
    r = __builtin_amdgcn_fractf(r);
    return __builtin_amdgcn_cosf(r);
}

// ---------------- k_prep: pad-transpose + border zero + weight packs ----------------
#define NB_TR 1024   // 4 b * 128 h * 2 wtiles
#define NB_BZ 516    // 4*516*64/256
#define NB_WR 288    // 73728/256
#define NB_WPM 36    // 9216/256

__global__ __launch_bounds__(256) void k_prep(
    const float* __restrict__ x,
    const float* __restrict__ w_b, const float* __restrict__ w_c,
    const float* __restrict__ w_p, const float* __restrict__ w_m,
    float* __restrict__ xp, unsigned short* __restrict__ wr8,
    unsigned short* __restrict__ wpm8)
{
    int bi = blockIdx.x;
    int tid = threadIdx.x;
    if (bi < NB_TR) {
        // transpose one (b, h, 64-wide w tile): x[b,c,h,w] -> xp[b,h+1,w+1,c]
        __shared__ float t[64][65];
        int b = bi >> 8;
        int h = (bi >> 1) & 127;
        int w0 = (bi & 1) * 64;
        int lane6 = tid & 63;
        for (int cc = tid >> 6; cc < 64; cc += 4)
            t[cc][lane6] = x[((b * 64 + cc) * 128 + h) * 128 + w0 + lane6];
        __syncthreads();
        for (int wsub = tid >> 6; wsub < 64; wsub += 4)
            xp[((size_t)(b * HP + h + 1) * WP + (w0 + wsub + 1)) * 64 + lane6] = t[lane6][wsub];
        return;
    }
    bi -= NB_TR;
    if (bi < NB_BZ) {
        // zero the padded border of xp
        int idx = bi * 256 + tid;            // < 4*516*64
        int c = idx & 63;
        int tt = idx >> 6;                   // 0..2063
        int b = tt / 516;
        int j = tt % 516;
        int hp, wp;
        if (j < 130)      { hp = 0;       wp = j; }
        else if (j < 260) { hp = 129;     wp = j - 130; }
        else if (j < 388) { hp = j - 259; wp = 0; }
        else              { hp = j - 387; wp = 129; }
        xp[((size_t)(b * HP + hp) * WP + wp) * 64 + c] = 0.f;
        return;
    }
    bi -= NB_BZ;
    if (bi < NB_WR) {
        // main-GEMM A pack: wr8[kk][ot][lane][j] = W[o=ot*16+(lane&15)][k=kk*32+(lane>>4)*8+j]
        int idx = bi * 256 + tid;            // < 73728
        int j    = idx & 7;
        int lane = (idx >> 3) & 63;
        int ot   = (idx >> 9) & 3;
        int kk   = idx >> 11;
        int o  = ot * 16 + (lane & 15);
        int k  = kk * 32 + (lane >> 4) * 8 + j;
        int slot = k >> 6;
        int c    = k & 63;
        float v;
        if (slot < 9) v = w_b[((o * CC + c) * 3 + slot / 3) * 3 + slot % 3];
        else { int n = slot - 9; v = w_c[((o * CC + c) * 3 + n / 3) * 3 + n % 3]; }
        wr8[idx] = f2bf(v);
        return;
    }
    bi -= NB_WR;
    {
        // offset/mask-conv A pack: wpm8[kk][lane][j] = Wpm[ch=lane&15][k=kk*32+(lane>>4)*8+j]
        int idx = bi * 256 + tid;            // < 9216
        if (idx >= NKC * 64 * 8) return;
        int j    = idx & 7;
        int lane = (idx >> 3) & 63;
        int kk   = idx >> 9;                 // 0..17
        int ch = lane & 15;
        int k  = kk * 32 + (lane >> 4) * 8 + j;   // 0..575
        int tap = k >> 6;
        int c   = k & 63;
        float v = 0.f;
        if (ch < 3)       v = w_p[((ch * CC + c) * 3 + tap / 3) * 3 + tap % 3];
        else if (ch < 12) v = w_m[(((ch - 3) * CC + c) * 3 + tap / 3) * 3 + tap % 3];
        wpm8[idx] = f2bf(v);
    }
}

// ---------------- k_main: fused offsets + gather + dual GEMM ----------------
// 512 threads = 8 waves, 32 pixels/block — round 8 structure verbatim
// (empirical optimum across rounds 8-15: ILP/byte/occupancy/setprio/tile/K-split
// levers all neutral-to-negative). ~57% L1 line-touch + ~46% VALU + serial
// phase chain co-limit at this source level.
// LDS U: two 16-pixel halves; element (k, p16) at 16B-block blk=(k>>3)*16+(p16^((k>>3)&15)).
__global__ __launch_bounds__(512, 4) void k_main(
    const float* __restrict__ xp, const unsigned short* __restrict__ wr8,
    const unsigned short* __restrict__ wpm8,
    const float* __restrict__ w_p,
    const float* __restrict__ b_p, const float* __restrict__ b_m,
    const float* __restrict__ b_b, float* __restrict__ out)
{
    __shared__ unsigned short U8[2 * 18432];   // 73,728 B
    __shared__ float wth[16][9][4];            // f32 theta-channel weights: [cq][tap][e]

    int tid = threadIdx.x;
    int lane = tid & 63;
    int g = tid >> 6;                 // wave 0..7
    int p_sub = lane >> 4;            // 0..3
    int cq = lane & 15;
    int c0 = cq * 4;

    // XCD-aware swizzle (2048 blocks, divisible by 8)
    int bid = blockIdx.x;
    int swz = (bid & 7) * 256 + (bid >> 3);
    int pixBase = swz * PIXT;

    // fill theta-weight table: wth[cq][tap][e] = w_p[ch=2][c=cq*4+e][tap/3][tap%3]
    for (int i = tid; i < 576; i += 512) {
        int cqi = i / 36;
        int rest = i % 36;
        int tap = rest >> 2;
        int e = rest & 3;
        int c = cqi * 4 + e;
        wth[cqi][tap][e] = w_p[((2 * CC + c) * 3 + tap / 3) * 3 + tap % 3];
    }
    __syncthreads();

    int p_local = g * 4 + p_sub;                 // 0..31
    int ph = p_local >> 4;
    int p16 = p_local & 15;
    int pix = pixBase + p_local;
    int b = pix >> 14;
    int h = (pix >> 7) & 127;
    int w = pix & 127;
    const float* xb = xp + (size_t)b * HP * WP * 64;

    // ---- phase 1a: fixed taps -> U slots 0..8 (bf16) + f32 theta partial
    float th = 0.f;
#pragma unroll
    for (int tap = 0; tap < 9; ++tap) {
        int ti = tap / 3, tj = tap % 3;
        float4 xv = *(const float4*)&xb[((h + ti) * WP + (w + tj)) * 64 + c0];
        float4 wt = *(const float4*)&wth[cq][tap][0];
        th += xv.x * wt.x + xv.y * wt.y + xv.z * wt.z + xv.w * wt.w;
        int k = tap * 64 + c0;
        int kqt = k >> 3;
        int blk = kqt * 16 + (p16 ^ (kqt & 15));
        bf16x4 pk;
        pk[0] = (short)f2bfh(xv.x); pk[1] = (short)f2bfh(xv.y);
        pk[2] = (short)f2bfh(xv.z); pk[3] = (short)f2bfh(xv.w);
        *(bf16x4*)&U8[ph * 18432 + blk * 8 + (k & 7)] = pk;
    }
    // reduce theta over the 16 lanes (cq) of the pixel-group
    th += __shfl_xor(th, 1);
    th += __shfl_xor(th, 2);
    th += __shfl_xor(th, 4);
    th += __shfl_xor(th, 8);
    // no __syncthreads here — phase 1b only reads this wave's own
    // U-slots 0..8; other waves' concurrent writes are to disjoint addresses.

    // ---- phase 1b: 12-ch offset/mask conv via MFMA on this wave's own 4 pixels.
    int kq = lane >> 4;
    f32x4 ca = {0.f, 0.f, 0.f, 0.f}, cb = {0.f, 0.f, 0.f, 0.f};
    {
        int colp = lane & 3;
        int pabs = g * 4 + colp;
        int phc = g >> 2;
        int p16c = pabs & 15;
        const bf16x8* av = (const bf16x8*)wpm8;
#pragma unroll
        for (int kk = 0; kk < NKC; ++kk) {
            bf16x8 a = av[kk * 64 + lane];
            int kqt = kk * 4 + kq;
            int blk = kqt * 16 + (p16c ^ (kqt & 15));
            bf16x8 bf = *(const bf16x8*)&U8[phc * 18432 + blk * 8];
            if (kk & 1) cb = __builtin_amdgcn_mfma_f32_16x16x32_bf16(a, bf, cb, 0, 0, 0);
            else        ca = __builtin_amdgcn_mfma_f32_16x16x32_bf16(a, bf, ca, 0, 0, 0);
        }
        ca[0] += cb[0]; ca[1] += cb[1]; ca[2] += cb[2]; ca[3] += cb[3];
    }

    // ---- deduped record math ----
    // conv D layout (verified r2/r4): conv[ch] of pixel p lives in lane ((ch>>2)<<4)+p, reg ch&3.
    int base16 = p_sub << 4;
    int chc = (cq < 9) ? (3 + cq) : 3;
    int srcL = ((chc >> 2) << 4) + p_sub;
    float m0 = __shfl(ca[0], srcL);
    float m1 = __shfl(ca[1], srcL);
    float m2 = __shfl(ca[2], srcL);
    float m3 = __shfl(ca[3], srcL);
    int jj = chc & 3;
    float cm = (jj == 0) ? m0 : (jj == 1) ? m1 : (jj == 2) ? m2 : m3;
    float c0v = __shfl(ca[0], p_sub);    // conv[0] (l channel)
    float c1v = __shfl(ca[1], p_sub);    // conv[1] (wd channel)

    float bp0 = b_p[0], bp1 = b_p[1], bp2 = b_p[2];
    float hval = 0.f;
    if (cq == 9)       hval = fsig_(fsin_(c0v + bp0)) * 48.5f + 1.5f;
    else if (cq == 10) hval = fsig_(fsin_(c1v + bp1)) * 48.5f + 1.5f;
    else if (cq == 11) hval = fcos_(fsig_(fsin_(th + bp2)) * 3.1415926f);
    else if (cq == 12) hval = fsin_(fsig_(fsin_(th + bp2)) * 3.1415926f);
    float l  = __shfl(hval, base16 + 9);
    float wd = __shfl(hval, base16 + 10);
    float ct = __shfl(hval, base16 + 11);
    float st = __shfl(hval, base16 + 12);

    // one record per lane (sample n = cq; lanes cq>=9 produce unread garbage)
    unsigned int qpack; float glt, grb, glb, grt;
    {
        int n = (cq < 9) ? cq : 8;
        float mm = fsig_(cm + b_m[n]);
        float pnx = (float)(n / 3 - 1);
        float pny = (float)(n % 3 - 1);
        float px = (float)(h + 1) + (l * (1.f / 3.f)) * pnx;
        float py = (float)(w + 1) + (wd * (1.f / 3.f)) * pny;
        float pxx = px * ct - py * st;
        float pyy = px * st + py * ct;
        float fx = floorf(pxx);
        float fy = floorf(pyy);
        int qltx = min(max((int)fx, 0), HP - 1);
        int qlty = min(max((int)fy, 0), WP - 1);
        int qrbx = min(max((int)fx + 1, 0), HP - 1);
        int qrby = min(max((int)fy + 1, 0), WP - 1);
        float pcx = fminf(fmaxf(pxx, 0.f), (float)(HP - 1));
        float pcy = fminf(fmaxf(pyy, 0.f), (float)(WP - 1));
        float dltx = 1.f + ((float)qltx - pcx);
        float drbx = 1.f - ((float)qrbx - pcx);
        float dlty = 1.f + ((float)qlty - pcy);
        float drby = 1.f - ((float)qrby - pcy);
        glt = dltx * dlty * mm;
        grb = drbx * drby * mm;
        glb = dltx * drby * mm;
        grt = drbx * dlty * mm;
        qpack = (unsigned)qltx | ((unsigned)qlty << 8) |
                ((unsigned)qrbx << 16) | ((unsigned)qrby << 24);
    }

    // ---- hoisted record broadcast: all 9 samples' addresses/weights into regs
    unsigned int qn[9];
    float wlt[9], wrb[9], wlb[9], wrt[9];
#pragma unroll
    for (int n = 0; n < 9; ++n) {
        qn[n]  = __shfl(qpack, base16 + n);
        wlt[n] = __shfl(glt, base16 + n);
        wrb[n] = __shfl(grb, base16 + n);
        wlb[n] = __shfl(glb, base16 + n);
        wrt[n] = __shfl(grt, base16 + n);
    }

    // ---- phase 1c: deformable gathers -> U slots 9..17 (addresses all ready)
#pragma unroll
    for (int n = 0; n < 9; ++n) {
        unsigned int q = qn[n];
        int qltx = q & 255, qlty = (q >> 8) & 255;
        int qrbx = (q >> 16) & 255, qrby = (q >> 24) & 255;
        float4 xlt = *(const float4*)&xb[(qltx * WP + qlty) * 64 + c0];
        float4 xrb = *(const float4*)&xb[(qrbx * WP + qrby) * 64 + c0];
        float4 xlb = *(const float4*)&xb[(qltx * WP + qrby) * 64 + c0];
        float4 xrt = *(const float4*)&xb[(qrbx * WP + qlty) * 64 + c0];
        float g_lt = wlt[n], g_rb = wrb[n], g_lb = wlb[n], g_rt = wrt[n];
        float v0 = g_lt * xlt.x + g_rb * xrb.x + g_lb * xlb.x + g_rt * xrt.x;
        float v1 = g_lt * xlt.y + g_rb * xrb.y + g_lb * xlb.y + g_rt * xrt.y;
        float v2 = g_lt * xlt.z + g_rb * xrb.z + g_lb * xlb.z + g_rt * xrt.z;
        float v3 = g_lt * xlt.w + g_rb * xrb.w + g_lb * xlb.w + g_rt * xrt.w;
        int k = (9 + n) * 64 + c0;
        int kqt = k >> 3;
        int blk = kqt * 16 + (p16 ^ (kqt & 15));
        bf16x4 pk;
        pk[0] = (short)f2bfh(v0); pk[1] = (short)f2bfh(v1);
        pk[2] = (short)f2bfh(v2); pk[3] = (short)f2bfh(v3);
        *(bf16x4*)&U8[ph * 18432 + blk * 8 + (k & 7)] = pk;
    }
    __syncthreads();

    // ---- phase 2: main GEMM, wave (ot=g&3, ph2=g>>2): 16 o x 16 pixels, K=1152
    int ot = g & 3;
    int ph2 = g >> 2;
    int pn = lane & 15;
    f32x4 a0 = {0.f, 0.f, 0.f, 0.f}, a1 = {0.f, 0.f, 0.f, 0.f};
    const bf16x8* wv = (const bf16x8*)wr8;
#pragma unroll
    for (int kk = 0; kk < NKK; ++kk) {
        bf16x8 a = wv[(kk * 4 + ot) * 64 + lane];
        int kqt = kk * 4 + kq;
        int blk = kqt * 16 + (pn ^ (kqt & 15));
        bf16x8 bf = *(const bf16x8*)&U8[ph2 * 18432 + blk * 8];
        if (kk & 1) a1 = __builtin_amdgcn_mfma_f32_16x16x32_bf16(a, bf, a1, 0, 0, 0);
        else        a0 = __builtin_amdgcn_mfma_f32_16x16x32_bf16(a, bf, a0, 0, 0, 0);
    }

    int pix2 = pixBase + ph2 * 16 + pn;
    int bb2 = pix2 >> 14;
    int hw = pix2 & 16383;
#pragma unroll
    for (int r2 = 0; r2 < 4; ++r2) {
        int o = ot * 16 + kq * 4 + r2;
        out[((size_t)(bb2 * 64 + o)) * 16384 + hw] = a0[r2] + a1[r2] + b_b[o];
    }
}

extern "C" void kernel_launch(void* const* d_in, const int* in_sizes, int n_in,
                              void* d_out, int out_size, void* d_ws, size_t ws_size,
                              hipStream_t stream) {
    const float* x   = (const float*)d_in[0];
    const float* w_b = (const float*)d_in[1];
    const float* b_b = (const float*)d_in[2];
    const float* w_p = (const float*)d_in[3];
    const float* b_p = (const float*)d_in[4];
    const float* w_m = (const float*)d_in[5];
    const float* b_m = (const float*)d_in[6];
    const float* w_c = (const float*)d_in[7];
    float* out = (float*)d_out;

    float* ws = (float*)d_ws;
    float* xp = ws + XP_OFF;
    unsigned short* wr8  = (unsigned short*)(ws + WR8_OFF);
    unsigned short* wpm8 = (unsigned short*)(ws + WPM8_OFF);

    k_prep<<<NB_TR + NB_BZ + NB_WR + NB_WPM, 256, 0, stream>>>(
        x, w_b, w_c, w_p, w_m, xp, wr8, wpm8);
    k_main<<<(BB * HH * WW) / PIXT, 512, 0, stream>>>(
        xp, wr8, wpm8, w_p, b_p, b_m, b_b, out);
}